// Round 1
// baseline (2921.596 us; speedup 1.0000x reference)
//
#include <hip/hip_runtime.h>

constexpr int NROW = 50000;
constexpr int NCOL = 50000;
constexpr int DH   = 128;

// ---- degree counting (unweighted, per relation) ----
__global__ void deg_count(const int* __restrict__ src, const int* __restrict__ dst,
                          float* __restrict__ cnt_src, float* __restrict__ cnt_dst, int E) {
    int stride = gridDim.x * blockDim.x;
    for (int i = blockIdx.x * blockDim.x + threadIdx.x; i < E; i += stride) {
        atomicAdd(&cnt_src[src[i]], 1.0f);
        atomicAdd(&cnt_dst[dst[i]], 1.0f);
    }
}

// in-place: a = 1/sqrt(max(a,1))
__global__ void rsqrt_clamp(float* __restrict__ a, int n) {
    int stride = gridDim.x * blockDim.x;
    for (int i = blockIdx.x * blockDim.x + threadIdx.x; i < n; i += stride)
        a[i] = 1.0f / sqrtf(fmaxf(a[i], 1.0f));
}

// ---- edge scatter: agg[dst] += h[src] * rout[src] * w_e ----
template <int D>
__global__ void scatter_add(const float* __restrict__ h, const int* __restrict__ src,
                            const int* __restrict__ dst, const float* __restrict__ w,
                            const float* __restrict__ rout, float* __restrict__ agg, int E) {
    constexpr int LOG = (D == 64) ? 6 : 7;
    const int total = E * D;
    const int stride = gridDim.x * blockDim.x;
    for (int i = blockIdx.x * blockDim.x + threadIdx.x; i < total; i += stride) {
        const int e = i >> LOG;
        const int f = i & (D - 1);
        const int s = src[e];
        const int d = dst[e];
        const float scale = w[e] * rout[s];
        atomicAdd(&agg[d * D + f], h[s * D + f] * scale);
    }
}

// ---- dense epilogue: out[node,:] = relu(rin[node] * (agg[node,:] @ W) + b) ----
template <int K>
__global__ void dense_relu(const float* __restrict__ agg, const float* __restrict__ rin,
                           const float* __restrict__ W, const float* __restrict__ b,
                           float* __restrict__ out, int n) {
    __shared__ float a[K];
    const int t = threadIdx.x;            // 0..127 (one output column each)
    const float bias = b[t];
    for (int node = blockIdx.x; node < n; node += gridDim.x) {
        if (t < K) a[t] = agg[node * K + t];
        __syncthreads();
        float sum = 0.f;
#pragma unroll 8
        for (int k = 0; k < K; ++k) sum = fmaf(a[k], W[k * DH + t], sum);
        out[node * DH + t] = fmaxf(fmaf(rin[node], sum, bias), 0.f);
        __syncthreads();
    }
}

// ---- layer-2 dense + fused column-mean accumulation into d_out ----
template <int K>
__global__ void dense_relu_meansum(const float* __restrict__ agg, const float* __restrict__ rin,
                                   const float* __restrict__ W, const float* __restrict__ b,
                                   float* __restrict__ out, int n, float invn) {
    __shared__ float a[K];
    const int t = threadIdx.x;
    const float bias = b[t];
    float acc = 0.f;
    for (int node = blockIdx.x; node < n; node += gridDim.x) {
        if (t < K) a[t] = agg[node * K + t];
        __syncthreads();
        float sum = 0.f;
#pragma unroll 8
        for (int k = 0; k < K; ++k) sum = fmaf(a[k], W[k * DH + t], sum);
        acc += fmaxf(fmaf(rin[node], sum, bias), 0.f);
        __syncthreads();
    }
    atomicAdd(&out[t], acc * invn);       // 256 blocks -> 256 adds per column, cheap
}

extern "C" void kernel_launch(void* const* d_in, const int* in_sizes, int n_in,
                              void* d_out, int out_size, void* d_ws, size_t ws_size,
                              hipStream_t stream) {
    const float* feat_row = (const float*)d_in[0];
    const float* feat_col = (const float*)d_in[1];
    const int*   src_rc   = (const int*)d_in[2];
    const int*   dst_rc   = (const int*)d_in[3];
    const float* w_rc     = (const float*)d_in[4];
    const int*   src_cr   = (const int*)d_in[5];
    const int*   dst_cr   = (const int*)d_in[6];
    const float* w_cr     = (const float*)d_in[7];
    const float* W0_rc    = (const float*)d_in[8];
    const float* b0_rc    = (const float*)d_in[9];
    const float* W0_cr    = (const float*)d_in[10];
    const float* b0_cr    = (const float*)d_in[11];
    const float* W1_rc    = (const float*)d_in[12];
    const float* b1_rc    = (const float*)d_in[13];
    const float* W1_cr    = (const float*)d_in[14];
    const float* b1_cr    = (const float*)d_in[15];
    const int E = in_sizes[2];
    float* out = (float*)d_out;

    // workspace layout (fp32): 4 norm arrays + 4 [50000 x 128] buffers = ~103 MB
    float* ws       = (float*)d_ws;
    float* r_out_rc = ws;                          // N_ROW
    float* r_in_rc  = ws + NROW;                   // N_COL
    float* r_out_cr = ws + NROW + NCOL;            // N_COL
    float* r_in_cr  = ws + NROW + 2 * NCOL;        // N_ROW
    float* agg_col  = ws + 200000;
    float* agg_row  = agg_col + (size_t)NCOL * DH;
    float* h_col1   = agg_row + (size_t)NROW * DH;
    float* h_row1   = h_col1  + (size_t)NCOL * DH;

    // degree norms (shared by both layers)
    hipMemsetAsync(ws, 0, 200000 * sizeof(float), stream);
    deg_count<<<1024, 256, 0, stream>>>(src_rc, dst_rc, r_out_rc, r_in_rc, E);
    deg_count<<<1024, 256, 0, stream>>>(src_cr, dst_cr, r_out_cr, r_in_cr, E);
    rsqrt_clamp<<<(200000 + 255) / 256, 256, 0, stream>>>(ws, 200000);

    // ---- layer 1: row -> col ----
    hipMemsetAsync(agg_col, 0, (size_t)NCOL * 64 * sizeof(float), stream);
    scatter_add<64><<<2048, 256, 0, stream>>>(feat_row, src_rc, dst_rc, w_rc, r_out_rc, agg_col, E);
    dense_relu<64><<<2048, 128, 0, stream>>>(agg_col, r_in_rc, W0_rc, b0_rc, h_col1, NCOL);

    // ---- layer 1: col -> row ----
    hipMemsetAsync(agg_row, 0, (size_t)NROW * 64 * sizeof(float), stream);
    scatter_add<64><<<2048, 256, 0, stream>>>(feat_col, src_cr, dst_cr, w_cr, r_out_cr, agg_row, E);
    dense_relu<64><<<2048, 128, 0, stream>>>(agg_row, r_in_cr, W0_cr, b0_cr, h_row1, NROW);

    hipMemsetAsync(out, 0, DH * sizeof(float), stream);

    // ---- layer 2: row -> col (src feats = h_row1) + fused mean over cols ----
    hipMemsetAsync(agg_col, 0, (size_t)NCOL * DH * sizeof(float), stream);
    scatter_add<128><<<4096, 256, 0, stream>>>(h_row1, src_rc, dst_rc, w_rc, r_out_rc, agg_col, E);
    dense_relu_meansum<128><<<256, 128, 0, stream>>>(agg_col, r_in_rc, W1_rc, b1_rc, out, NCOL, 1.0f / NCOL);

    // ---- layer 2: col -> row (src feats = h_col1) + fused mean over rows ----
    hipMemsetAsync(agg_row, 0, (size_t)NROW * DH * sizeof(float), stream);
    scatter_add<128><<<4096, 256, 0, stream>>>(h_col1, src_cr, dst_cr, w_cr, r_out_cr, agg_row, E);
    dense_relu_meansum<128><<<256, 128, 0, stream>>>(agg_row, r_in_cr, W1_cr, b1_cr, out, NROW, 1.0f / NROW);
}